// Round 10
// baseline (424.462 us; speedup 1.0000x reference)
//
#include <hip/hip_runtime.h>
#include <math.h>

// AttentionBlock: B=8, C=256, HW=4096. Round 10: split-j flash attention.
//   K1  gn_stats, K1b affine_transpose, K2 qkv_gemm: unchanged from R9.
//   K3  attn: grid 2048 = (b, part=4, i-tile). Each block does 1024 j.
//       Writes UNNORMALIZED O partial (bf16 [n][c]) + per-row (m,l).
//   K3b attn_combine: 512 blocks; merges 4 partials in place into part-0 slot.
//   K4  out_gemm: reads part-0 slots directly (tmpT eliminated).
// ws: s,t 16KB | Qt 16M | Kt 16M | Vb 16M | nxT 16M (overlaid by pO 64M) | pML 1M = 113MB

#define Bn 8
#define Cn 256
#define HWn 4096
#define Gn 8
#define CPGn 32
#define Mqkv 768
#define EPSf 1e-5f
#define QSCALEf 0.0625f   // 1/sqrt(256), exact in bf16
#define RTHR 8.0f

typedef short bf16x8 __attribute__((ext_vector_type(8)));
typedef float f32x4 __attribute__((ext_vector_type(4)));

__device__ __forceinline__ unsigned short f2bf(float f) {
  union { float f; unsigned u; } v; v.f = f;
  unsigned r = v.u + 0x7FFFu + ((v.u >> 16) & 1u);  // RNE
  return (unsigned short)(r >> 16);
}

__device__ __forceinline__ float bf2f(unsigned short u) {
  union { unsigned u; float f; } v; v.u = ((unsigned)u) << 16;
  return v.f;
}

__device__ __forceinline__ int cvt_pk_bf16(float lo, float hi) {
  int d;
  asm("v_cvt_pk_bf16_f32 %0, %1, %2" : "=v"(d) : "v"(lo), "v"(hi));
  return d;
}

// ---------------- K1: group-norm stats -> per-channel affine ----------------
__global__ __launch_bounds__(1024)
void gn_stats_kernel(const float* __restrict__ x, const float* __restrict__ gn_w,
                     const float* __restrict__ gn_b, float* __restrict__ s_out,
                     float* __restrict__ t_out) {
  const int b = blockIdx.x / Gn, g = blockIdx.x % Gn;
  const float4* base = (const float4*)(x + ((size_t)(b * Cn + g * CPGn)) * HWn);
  const int n4 = CPGn * HWn / 4;
  float sum = 0.f, sq = 0.f;
  for (int i = threadIdx.x; i < n4; i += 1024) {
    float4 v = base[i];
    sum += (v.x + v.y) + (v.z + v.w);
    sq  += (v.x * v.x + v.y * v.y) + (v.z * v.z + v.w * v.w);
  }
  __shared__ float ss[1024], s2[1024];
  ss[threadIdx.x] = sum; s2[threadIdx.x] = sq;
  __syncthreads();
  for (int off = 512; off > 0; off >>= 1) {
    if ((int)threadIdx.x < off) {
      ss[threadIdx.x] += ss[threadIdx.x + off];
      s2[threadIdx.x] += s2[threadIdx.x + off];
    }
    __syncthreads();
  }
  if (threadIdx.x < CPGn) {
    const float inv_n = 1.f / (float)(CPGn * HWn);
    float mean = ss[0] * inv_n;
    float var  = s2[0] * inv_n - mean * mean;
    float rstd = rsqrtf(var + EPSf);
    int c = g * CPGn + (int)threadIdx.x;
    float sc = gn_w[c] * rstd;
    s_out[b * Cn + c] = sc;
    t_out[b * Cn + c] = gn_b[c] - mean * sc;
  }
}

// ---------------- K1b: affine + transpose -> nxT[b][n][c] bf16 ----------------
__global__ __launch_bounds__(256)
void affine_transpose_kernel(const float* __restrict__ x, const float* __restrict__ s_aff,
                             const float* __restrict__ t_aff, unsigned short* __restrict__ nxT) {
  const int bid = blockIdx.x;
  const int b = bid & 7, r = bid >> 3;
  const int c0 = (r & 3) * 64, n0 = (r >> 2) * 64;
  const int tid = threadIdx.x;
  __shared__ unsigned int ld32[64][33];
  const float* xb = x + ((size_t)(b * Cn + c0)) * HWn + n0;
  const int cl0 = tid >> 4, nn = (tid & 15) * 4;
#pragma unroll
  for (int it = 0; it < 4; ++it) {
    int cl = cl0 + 16 * it;
    int c = c0 + cl;
    float sc = s_aff[b * Cn + c], sh = t_aff[b * Cn + c];
    float4 v = *(const float4*)(xb + (size_t)cl * HWn + nn);
    ld32[cl][(nn >> 1) + 0] = (unsigned)cvt_pk_bf16(v.x * sc + sh, v.y * sc + sh);
    ld32[cl][(nn >> 1) + 1] = (unsigned)cvt_pk_bf16(v.z * sc + sh, v.w * sc + sh);
  }
  __syncthreads();
#pragma unroll
  for (int it = 0; it < 2; ++it) {
    int chunk = tid + 256 * it;
    int n = chunk >> 3, cg = chunk & 7;
    union { unsigned short u[8]; bf16x8 v; } o;
#pragma unroll
    for (int k = 0; k < 8; ++k) {
      unsigned w32 = ld32[cg * 8 + k][n >> 1];
      o.u[k] = (unsigned short)((n & 1) ? (w32 >> 16) : (w32 & 0xffffu));
    }
    *(bf16x8*)(nxT + ((size_t)(b * HWn + n0 + n)) * Cn + c0 + cg * 8) = o.v;
  }
}

// ---------------- K2: QKV GEMM, LDS-free bf16 MFMA ----------------
__global__ __launch_bounds__(256, 2)
void qkv_gemm_kernel(const unsigned short* __restrict__ nxT, const float* __restrict__ w,
                     const float* __restrict__ wb, unsigned short* __restrict__ Qt,
                     unsigned short* __restrict__ Kt, unsigned short* __restrict__ Vb) {
  const int bid = blockIdx.x;
  const int b = bid & 7, r = bid >> 3;
  const int n0 = (r & 63) * 64, m0 = (r >> 6) * 128;
  const int tid = threadIdx.x;
  const int wv = tid >> 6, l = tid & 63;
  const int l15 = l & 15, lq = l >> 4;
  const int ob = m0 + wv * 32;

  bf16x8 wf[2][8];
#pragma unroll
  for (int g = 0; g < 2; ++g) {
    const float* wr = w + (size_t)(ob + g * 16 + l15) * Cn + lq * 8;
#pragma unroll
    for (int kc = 0; kc < 8; ++kc) {
      float4 a = *(const float4*)(wr + kc * 32);
      float4 c4 = *(const float4*)(wr + kc * 32 + 4);
      union { int w4[4]; bf16x8 v; } u;
      u.w4[0] = cvt_pk_bf16(a.x, a.y);  u.w4[1] = cvt_pk_bf16(a.z, a.w);
      u.w4[2] = cvt_pk_bf16(c4.x, c4.y); u.w4[3] = cvt_pk_bf16(c4.z, c4.w);
      wf[g][kc] = u.v;
    }
  }

  const unsigned short* nb = nxT + (size_t)b * HWn * Cn + lq * 8;
  f32x4 acc[2][4];
#pragma unroll
  for (int g = 0; g < 2; ++g)
#pragma unroll
    for (int s = 0; s < 4; ++s) acc[g][s] = (f32x4)(0.f);

  const bool isV = (m0 >= 512);
#pragma unroll
  for (int s = 0; s < 4; ++s) {
    const unsigned short* np = nb + (size_t)(n0 + s * 16 + l15) * Cn;
#pragma unroll
    for (int kc = 0; kc < 8; ++kc) {
      bf16x8 xf = *(const bf16x8*)(np + kc * 32);
      if (!isV) {
        acc[0][s] = __builtin_amdgcn_mfma_f32_16x16x32_bf16(wf[0][kc], xf, acc[0][s], 0, 0, 0);
        acc[1][s] = __builtin_amdgcn_mfma_f32_16x16x32_bf16(wf[1][kc], xf, acc[1][s], 0, 0, 0);
      } else {
        acc[0][s] = __builtin_amdgcn_mfma_f32_16x16x32_bf16(xf, wf[0][kc], acc[0][s], 0, 0, 0);
        acc[1][s] = __builtin_amdgcn_mfma_f32_16x16x32_bf16(xf, wf[1][kc], acc[1][s], 0, 0, 0);
      }
    }
  }

  if (!isV) {
    unsigned short* dst = (m0 < 256) ? Qt : Kt;
    const float scl = (m0 < 256) ? QSCALEf : 1.0f;
#pragma unroll
    for (int g = 0; g < 2; ++g) {
      int cb = ((ob + g * 16) & 255) + lq * 4;
      float b0 = wb[ob + g * 16 + lq * 4 + 0];
      float b1 = wb[ob + g * 16 + lq * 4 + 1];
      float b2 = wb[ob + g * 16 + lq * 4 + 2];
      float b3 = wb[ob + g * 16 + lq * 4 + 3];
#pragma unroll
      for (int s = 0; s < 4; ++s) {
        int n = n0 + s * 16 + l15;
        ushort4 pk;
        pk.x = f2bf((acc[g][s][0] + b0) * scl);
        pk.y = f2bf((acc[g][s][1] + b1) * scl);
        pk.z = f2bf((acc[g][s][2] + b2) * scl);
        pk.w = f2bf((acc[g][s][3] + b3) * scl);
        *(ushort4*)(dst + ((size_t)(b * HWn + n)) * Cn + cb) = pk;
      }
    }
  } else {
#pragma unroll
    for (int g = 0; g < 2; ++g) {
      int o = ob + g * 16 + l15;
      int c = o - 512;
      float bias = wb[o];
#pragma unroll
      for (int s = 0; s < 4; ++s) {
        int n = n0 + s * 16 + lq * 4;
        ushort4 pk;
        pk.x = f2bf(acc[g][s][0] + bias);
        pk.y = f2bf(acc[g][s][1] + bias);
        pk.z = f2bf(acc[g][s][2] + bias);
        pk.w = f2bf(acc[g][s][3] + bias);
        *(ushort4*)(Vb + ((size_t)(b * Cn + c)) * HWn + n) = pk;
      }
    }
  }
}

// ---------------- K3: split-j flash attention ----------------
// grid 2048: b=bid&7, part=(bid>>3)&3, i0=(bid>>5)*64. Each block: j in [part*1024, +1024).
// Partial out: pO[bid] = 64 rows x 256 c bf16 [n][c], UNNORMALIZED; pML[bid] = 64 x (m,l).
__global__ __launch_bounds__(256, 2)
void attn_kernel(const unsigned short* __restrict__ Qt,
                 const unsigned short* __restrict__ Kt,
                 const unsigned short* __restrict__ Vb,
                 unsigned short* __restrict__ pO, float* __restrict__ pML) {
  const int bid = blockIdx.x;
  const int b = bid & 7, part = (bid >> 3) & 3, i0 = (bid >> 5) * 64;
  const int tid = threadIdx.x;
  const int wv = tid >> 6, l = tid & 63;
  const int l15 = l & 15, lq = l >> 4;

  __shared__ unsigned short Ks[8192];  // 16KB
  __shared__ unsigned short Vs[8192];  // 16KB
  char* KsB = (char*)Ks;
  char* VsB = (char*)Vs;

  const unsigned short* Qb = Qt + ((size_t)b * HWn + i0) * Cn;
  const unsigned short* Kb = Kt + (size_t)b * HWn * Cn;
  const unsigned short* Vg = Vb + (size_t)b * Cn * HWn;

  bf16x8 qf[8];
  {
    const unsigned short* qrow = Qb + (size_t)(wv * 16 + l15) * Cn + lq * 8;
#pragma unroll
    for (int kc = 0; kc < 8; ++kc) qf[kc] = *(const bf16x8*)(qrow + kc * 32);
  }

  const int jk = ((tid >> 6) & 1) * 16 + (tid & 15);
  const int ck = (tid >> 7) * 32 + ((tid >> 4) & 3) * 8;
  const int cv = (tid >> 6) * 16 + (tid & 15);
  const int jv = ((tid >> 4) & 3) * 8;
  const unsigned short* gK = Kb + (size_t)(jk + part * 1024) * Cn + ck;
  const unsigned short* gV = Vg + (size_t)cv * HWn + jv + part * 1024;

  const int laneA = l15 + ((lq & 1) << 5);
  const int laneB = laneA + 16;
  const int shi = lq >> 1;

  bf16x8 kst[4], vst[4];
#pragma unroll
  for (int q = 0; q < 4; ++q) kst[q] = *(const bf16x8*)(gK + q * 64);
#pragma unroll
  for (int q = 0; q < 4; ++q) vst[q] = *(const bf16x8*)(gV + (size_t)q * 64 * HWn);
  gK += 32 * Cn; gV += 32;

  f32x4 o_acc[16];
#pragma unroll
  for (int cs = 0; cs < 16; ++cs) o_acc[cs] = (f32x4)(0.f);
  float m_i = -INFINITY, l_i = 0.f;

#pragma unroll 1
  for (int t = 0; t < 32; ++t) {
#pragma unroll
    for (int q = 0; q < 4; ++q) *(bf16x8*)(KsB + tid * 16 + q * 4096) = kst[q];
#pragma unroll
    for (int q = 0; q < 4; ++q) *(bf16x8*)(VsB + tid * 16 + q * 4096) = vst[q];
    __syncthreads();
    if (t < 31) {
#pragma unroll
      for (int q = 0; q < 4; ++q) kst[q] = *(const bf16x8*)(gK + q * 64);
#pragma unroll
      for (int q = 0; q < 4; ++q) vst[q] = *(const bf16x8*)(gV + (size_t)q * 64 * HWn);
      gK += 32 * Cn; gV += 32;
    }

    f32x4 s0 = (f32x4)(0.f), s1 = (f32x4)(0.f);
#pragma unroll
    for (int kc = 0; kc < 8; ++kc) {
      bf16x8 kf0 = *(const bf16x8*)(KsB + l * 16 + kc * 2048);
      bf16x8 kf1 = *(const bf16x8*)(KsB + l * 16 + kc * 2048 + 1024);
      s0 = __builtin_amdgcn_mfma_f32_16x16x32_bf16(kf0, qf[kc], s0, 0, 0, 0);
      s1 = __builtin_amdgcn_mfma_f32_16x16x32_bf16(kf1, qf[kc], s1, 0, 0, 0);
    }

    float p[2][4];
#pragma unroll
    for (int u = 0; u < 4; ++u) { p[0][u] = s0[u]; p[1][u] = s1[u]; }
    float rm = fmaxf(fmaxf(fmaxf(p[0][0], p[0][1]), fmaxf(p[0][2], p[0][3])),
                     fmaxf(fmaxf(p[1][0], p[1][1]), fmaxf(p[1][2], p[1][3])));
    rm = fmaxf(rm, __shfl_xor(rm, 16));
    rm = fmaxf(rm, __shfl_xor(rm, 32));
    if (!__all(rm - m_i <= RTHR)) {
      float mn = fmaxf(m_i, rm);
      float alpha = __expf(m_i - mn);
      m_i = mn;
      l_i *= alpha;
      float a0 = __shfl(alpha, 4 * lq + 0);
      float a1 = __shfl(alpha, 4 * lq + 1);
      float a2 = __shfl(alpha, 4 * lq + 2);
      float a3 = __shfl(alpha, 4 * lq + 3);
#pragma unroll
      for (int cs = 0; cs < 16; ++cs) {
        o_acc[cs][0] *= a0; o_acc[cs][1] *= a1;
        o_acc[cs][2] *= a2; o_acc[cs][3] *= a3;
      }
    }
    float rs = 0.f;
#pragma unroll
    for (int s = 0; s < 2; ++s)
#pragma unroll
      for (int u = 0; u < 4; ++u) { float e = __expf(p[s][u] - m_i); p[s][u] = e; rs += e; }
    rs += __shfl_xor(rs, 16);
    rs += __shfl_xor(rs, 32);
    l_i += rs;

    int d00 = cvt_pk_bf16(p[0][0], p[0][1]), d01 = cvt_pk_bf16(p[0][2], p[0][3]);
    int d10 = cvt_pk_bf16(p[1][0], p[1][1]), d11 = cvt_pk_bf16(p[1][2], p[1][3]);
    int A00 = __shfl(d00, laneA), A01 = __shfl(d01, laneA);
    int A10 = __shfl(d10, laneA), A11 = __shfl(d11, laneA);
    int B00 = __shfl(d00, laneB), B01 = __shfl(d01, laneB);
    int B10 = __shfl(d10, laneB), B11 = __shfl(d11, laneB);
    union { int w[4]; bf16x8 v; } pa;
    pa.w[0] = shi ? A10 : A00; pa.w[1] = shi ? A11 : A01;
    pa.w[2] = shi ? B10 : B00; pa.w[3] = shi ? B11 : B01;

#pragma unroll
    for (int cs = 0; cs < 16; ++cs) {
      bf16x8 vf = *(const bf16x8*)(VsB + l * 16 + cs * 1024);
      o_acc[cs] = __builtin_amdgcn_mfma_f32_16x16x32_bf16(pa.v, vf, o_acc[cs], 0, 0, 0);
    }
    __syncthreads();
  }

  // ---- epilogue: store UNNORMALIZED partial [n][c] bf16 + (m,l) per row ----
  unsigned short* pOb = pO + (size_t)bid * (64 * 256);
  const int ibase = wv * 16 + lq * 4;  // local row
#pragma unroll
  for (int cs = 0; cs < 16; ++cs) {
    int c = cs * 16 + l15;
    pOb[(ibase + 0) * 256 + c] = f2bf(o_acc[cs][0]);
    pOb[(ibase + 1) * 256 + c] = f2bf(o_acc[cs][1]);
    pOb[(ibase + 2) * 256 + c] = f2bf(o_acc[cs][2]);
    pOb[(ibase + 3) * 256 + c] = f2bf(o_acc[cs][3]);
  }
  if (lq == 0) {
    pML[(size_t)bid * 128 + (wv * 16 + l15) * 2 + 0] = m_i;
    pML[(size_t)bid * 128 + (wv * 16 + l15) * 2 + 1] = l_i;
  }
}

// ---------------- K3b: combine 4 partials in place into part-0 slot ----------------
// grid 512: b=bid&7, itile=bid>>3. pbid(p) = b + (p<<3) + (itile<<5).
__global__ __launch_bounds__(256)
void attn_combine_kernel(unsigned short* __restrict__ pO, const float* __restrict__ pML) {
  const int bid = blockIdx.x;
  const int b = bid & 7, itile = bid >> 3;
  const int tid = threadIdx.x;
  const int p0id = b + (itile << 5);
  unsigned short* B0 = pO + (size_t)p0id * (64 * 256);
  const unsigned short* B1 = pO + (size_t)(p0id + 8)  * (64 * 256);
  const unsigned short* B2 = pO + (size_t)(p0id + 16) * (64 * 256);
  const unsigned short* B3 = pO + (size_t)(p0id + 24) * (64 * 256);

  __shared__ float gS[4][64];
  if (tid < 64) {
    float m0v = pML[(size_t)p0id * 128 + tid * 2],        l0v = pML[(size_t)p0id * 128 + tid * 2 + 1];
    float m1v = pML[(size_t)(p0id + 8) * 128 + tid * 2],  l1v = pML[(size_t)(p0id + 8) * 128 + tid * 2 + 1];
    float m2v = pML[(size_t)(p0id + 16) * 128 + tid * 2], l2v = pML[(size_t)(p0id + 16) * 128 + tid * 2 + 1];
    float m3v = pML[(size_t)(p0id + 24) * 128 + tid * 2], l3v = pML[(size_t)(p0id + 24) * 128 + tid * 2 + 1];
    float ms = fmaxf(fmaxf(m0v, m1v), fmaxf(m2v, m3v));
    float w0 = __expf(m0v - ms), w1 = __expf(m1v - ms);
    float w2 = __expf(m2v - ms), w3 = __expf(m3v - ms);
    float den = w0 * l0v + w1 * l1v + w2 * l2v + w3 * l3v;
    float id = 1.f / den;
    gS[0][tid] = w0 * id; gS[1][tid] = w1 * id;
    gS[2][tid] = w2 * id; gS[3][tid] = w3 * id;
  }
  __syncthreads();

#pragma unroll
  for (int k = 0; k < 8; ++k) {
    int chunk = tid + 256 * k;
    int row = chunk >> 5, cc = (chunk & 31) * 8;
    int off = row * 256 + cc;
    float g0 = gS[0][row], g1 = gS[1][row], g2 = gS[2][row], g3 = gS[3][row];
    union { unsigned short u[8]; bf16x8 v; } v0, v1, v2, v3, o;
    v0.v = *(const bf16x8*)(B0 + off);
    v1.v = *(const bf16x8*)(B1 + off);
    v2.v = *(const bf16x8*)(B2 + off);
    v3.v = *(const bf16x8*)(B3 + off);
#pragma unroll
    for (int e = 0; e < 8; ++e) {
      float val = g0 * bf2f(v0.u[e]) + g1 * bf2f(v1.u[e]) +
                  g2 * bf2f(v2.u[e]) + g3 * bf2f(v3.u[e]);
      o.u[e] = f2bf(val);
    }
    *(bf16x8*)(B0 + off) = o.v;
  }
}

// ---------------- K4: out projection, LDS-free bf16 MFMA (swapped) + residual ----------------
// Reads combined attention from pO part-0 slots: row n -> pbid0 = b + ((n>>6)<<5).
__global__ __launch_bounds__(256, 2)
void out_gemm_kernel(const unsigned short* __restrict__ pO, const float* __restrict__ w,
                     const float* __restrict__ wb, const float* __restrict__ xres,
                     float* __restrict__ y) {
  const int bid = blockIdx.x;
  const int b = bid & 7, r = bid >> 3;
  const int n0 = (r & 63) * 64, m0 = (r >> 6) * 128;
  const int tid = threadIdx.x;
  const int wv = tid >> 6, l = tid & 63;
  const int l15 = l & 15, lq = l >> 4;
  const int ob = m0 + wv * 32;

  bf16x8 wf[2][8];
#pragma unroll
  for (int g = 0; g < 2; ++g) {
    const float* wr = w + (size_t)(ob + g * 16 + l15) * Cn + lq * 8;
#pragma unroll
    for (int kc = 0; kc < 8; ++kc) {
      float4 a = *(const float4*)(wr + kc * 32);
      float4 c4 = *(const float4*)(wr + kc * 32 + 4);
      union { int w4[4]; bf16x8 v; } u;
      u.w4[0] = cvt_pk_bf16(a.x, a.y);  u.w4[1] = cvt_pk_bf16(a.z, a.w);
      u.w4[2] = cvt_pk_bf16(c4.x, c4.y); u.w4[3] = cvt_pk_bf16(c4.z, c4.w);
      wf[g][kc] = u.v;
    }
  }

  // part-0 slot for this n-tile (n0 is a multiple of 64)
  const unsigned short* tb = pO + ((size_t)(b + ((n0 >> 6) << 5)) * (64 * 256)) + lq * 8;
  f32x4 acc[2][4];
#pragma unroll
  for (int g = 0; g < 2; ++g)
#pragma unroll
    for (int s = 0; s < 4; ++s) acc[g][s] = (f32x4)(0.f);

#pragma unroll
  for (int s = 0; s < 4; ++s) {
    const unsigned short* tp = tb + (size_t)(s * 16 + l15) * Cn;
#pragma unroll
    for (int kc = 0; kc < 8; ++kc) {
      bf16x8 tf = *(const bf16x8*)(tp + kc * 32);
      acc[0][s] = __builtin_amdgcn_mfma_f32_16x16x32_bf16(tf, wf[0][kc], acc[0][s], 0, 0, 0);
      acc[1][s] = __builtin_amdgcn_mfma_f32_16x16x32_bf16(tf, wf[1][kc], acc[1][s], 0, 0, 0);
    }
  }

#pragma unroll
  for (int g = 0; g < 2; ++g) {
    int o = ob + g * 16 + l15;
    float bias = wb[o];
#pragma unroll
    for (int s = 0; s < 4; ++s) {
      int n = n0 + s * 16 + lq * 4;
      size_t idx = ((size_t)(b * Cn + o)) * HWn + n;
      float4 xr = *(const float4*)(xres + idx);
      float4 out;
      out.x = acc[g][s][0] + bias + xr.x;
      out.y = acc[g][s][1] + bias + xr.y;
      out.z = acc[g][s][2] + bias + xr.z;
      out.w = acc[g][s][3] + bias + xr.w;
      *(float4*)(y + idx) = out;
    }
  }
}

extern "C" void kernel_launch(void* const* d_in, const int* in_sizes, int n_in,
                              void* d_out, int out_size, void* d_ws, size_t ws_size,
                              hipStream_t stream) {
  (void)in_sizes; (void)n_in; (void)out_size; (void)ws_size;
  const float* x     = (const float*)d_in[0];
  const float* gn_w  = (const float*)d_in[1];
  const float* gn_b  = (const float*)d_in[2];
  const float* qkv_w = (const float*)d_in[3];
  const float* qkv_b = (const float*)d_in[4];
  const float* out_w = (const float*)d_in[5];
  const float* out_b = (const float*)d_in[6];
  float* out = (float*)d_out;

  char* ws = (char*)d_ws;
  const size_t BHC = (size_t)Bn * HWn * Cn;      // 8M elements
  float* s_aff = (float*)ws;                     // B*C
  float* t_aff = s_aff + Bn * Cn;                // B*C
  unsigned short* Qt  = (unsigned short*)(ws + 16384);   // 16MB
  unsigned short* Kt  = Qt + BHC;                        // 16MB
  unsigned short* Vb  = Kt + BHC;                        // 16MB
  unsigned short* nxT = Vb + BHC;                        // 16MB (dead after qkv)
  unsigned short* pO  = nxT;                             // overlays nxT; 2048*16384*2B = 64MB
  float* pML = (float*)((char*)pO + (size_t)2048 * 16384 * 2);  // 1MB

  gn_stats_kernel<<<dim3(Bn * Gn), 1024, 0, stream>>>(x, gn_w, gn_b, s_aff, t_aff);
  affine_transpose_kernel<<<dim3(2048), 256, 0, stream>>>(x, s_aff, t_aff, nxT);
  qkv_gemm_kernel<<<dim3(3072), 256, 0, stream>>>(nxT, qkv_w, qkv_b, Qt, Kt, Vb);
  attn_kernel<<<dim3(2048), 256, 0, stream>>>(Qt, Kt, Vb, pO, pML);
  attn_combine_kernel<<<dim3(512), 256, 0, stream>>>(pO, pML);
  out_gemm_kernel<<<dim3(1024), 256, 0, stream>>>(pO, out_w, out_b, x, out);
}